// Round 4
// baseline (6940.128 us; speedup 1.0000x reference)
//
#include <hip/hip_runtime.h>

// SDGCN32: 31-layer GCN, N=100k nodes, E=3.2M edges, F=32.
//  - hs = dis*h carried between layers in FP32 (fp16 carrier FAILED: 31-layer error amplification)
//  - CSR by dst, with each row's edges bucketed by src>>15 (4 buckets of 4MiB hs-chunks):
//    all blocks sweep buckets in phase -> per-XCD L2 working set ~= one chunk -> fewer L3 misses
//  - per-block LDS accumulator (98 nodes x 32ch fp32), self-term slab-copied in
//  - epilogue per node: *dis -> @W + b -> mynorm -> online out accumulation
//    out += mynorm(x_j)@Mn_j (+ raw x_j@Rw_j for j in {1,16})
//  - lane map: slot=lane>>3 walks every-8th edge, q=lane&7 owns channels 4q..4q+3

#define NPB 98      // nodes per block (LDS acc = 98*128B = 12.5 KB)
#define NB 4        // src buckets
#define BSHIFT 15   // bucket = src >> 15  (32768 nodes = 4 MiB fp32 chunk)

__device__ __forceinline__ float shflx(float v, int m) { return __shfl_xor(v, m, 64); }

// ---------- CSR build (per-(dst,bucket) segments) ----------
__global__ void k_hist(const int* __restrict__ src, const int* __restrict__ dst, int E,
                       int* __restrict__ cnt) {
    int e = blockIdx.x * blockDim.x + threadIdx.x;
    if (e < E) atomicAdd(&cnt[dst[e] * NB + (src[e] >> BSHIFT)], 1);
}

__global__ void k_scan1(const int* __restrict__ cnt, int M, int* __restrict__ row_ptr,
                        int* __restrict__ bsums) {
    __shared__ int s[512];
    int i = blockIdx.x * 512 + threadIdx.x;
    int v = (i < M) ? cnt[i] : 0;
    s[threadIdx.x] = v;
    __syncthreads();
    for (int off = 1; off < 512; off <<= 1) {
        int t = (threadIdx.x >= off) ? s[threadIdx.x - off] : 0;
        __syncthreads();
        s[threadIdx.x] += t;
        __syncthreads();
    }
    int incl = s[threadIdx.x];
    if (i < M) row_ptr[i] = incl - v;
    if (threadIdx.x == 511) bsums[blockIdx.x] = incl;
}

__global__ void k_scan2(int* __restrict__ bsums, int nb) {
    __shared__ int s[1024];
    int v = (threadIdx.x < nb) ? bsums[threadIdx.x] : 0;
    s[threadIdx.x] = v;
    __syncthreads();
    for (int off = 1; off < 1024; off <<= 1) {
        int t = (threadIdx.x >= off) ? s[threadIdx.x - off] : 0;
        __syncthreads();
        s[threadIdx.x] += t;
        __syncthreads();
    }
    if (threadIdx.x < nb) bsums[threadIdx.x] = s[threadIdx.x] - v;
}

__global__ void k_scan3(int* __restrict__ row_ptr, const int* __restrict__ bsums,
                        const int* __restrict__ cnt, int M, int E,
                        int* __restrict__ cursor, float* __restrict__ dis) {
    int i = blockIdx.x * 512 + threadIdx.x;
    if (i < M) {
        int rp = row_ptr[i] + bsums[blockIdx.x];
        row_ptr[i] = rp;
        cursor[i] = rp;
        if ((i & (NB - 1)) == 0) {
            float deg = (float)(cnt[i] + cnt[i + 1] + cnt[i + 2] + cnt[i + 3]);
            dis[i / NB] = rsqrtf(deg + 1.0f);
        }
    }
    if (i == 0) row_ptr[M] = E;
}

__global__ void k_fill(const int* __restrict__ src, const int* __restrict__ dst, int E,
                       int* __restrict__ cursor, int* __restrict__ csr_src) {
    int e = blockIdx.x * blockDim.x + threadIdx.x;
    if (e < E) {
        int s = src[e];
        int pos = atomicAdd(&cursor[dst[e] * NB + (s >> BSHIFT)], 1);
        csr_src[pos] = s;
    }
}

// ---------- coefficients, layout [j][o][c] ----------
__global__ void k_mnorm(const float* __restrict__ W2, float* __restrict__ Mn,
                        float* __restrict__ Rw) {
    int idx = blockIdx.x * blockDim.x + threadIdx.x;
    if (idx >= 32 * 32 * 10) return;
    int c = idx % 32, o = (idx / 32) % 10, j = idx / 320;
    float v = 0.f;
    if (j >= 2 && j != 16) v += W2[(32 * j + c) * 10 + o];
    if (j <= 29 && j != 14) v -= W2[(32 * (j + 2) + c) * 10 + o];
    Mn[idx] = v;
    Rw[idx] = (j == 0 || j == 1 || j == 16) ? W2[(32 * j + c) * 10 + o] : 0.f;
}

// ---------- layer 0: x0 = mynorm(relu(x@W1+b1)); out init ----------
__global__ __launch_bounds__(256) void k_x0(
    const float* __restrict__ x, const float* __restrict__ W1, const float* __restrict__ b1,
    const float* __restrict__ W2, const float* __restrict__ b2, const float* __restrict__ M0,
    const float* __restrict__ dis, float* __restrict__ hs, float* __restrict__ out, int N)
{
    __shared__ float Ws[64 * 32];
    for (int i = threadIdx.x; i < 64 * 32; i += 256) Ws[i] = W1[i];
    __syncthreads();
    int wave = threadIdx.x >> 6;
    int lane = threadIdx.x & 63;
    int c = lane & 31, half = lane >> 5;
    int n = blockIdx.x * 4 + wave;
    if (n >= N) return;

    float xr = x[n * 64 + lane];
    float acc = 0.f;
#pragma unroll
    for (int kk = 0; kk < 32; ++kk) {
        float xv = __shfl(xr, half * 32 + kk, 64);
        acc += xv * Ws[(half * 32 + kk) * 32 + c];
    }
    acc += shflx(acc, 32);
    acc += b1[c];
    acc = fmaxf(acc, 0.f);
    float mn = acc, mx = acc;
#pragma unroll
    for (int m = 1; m <= 16; m <<= 1) { mn = fminf(mn, shflx(mn, m)); mx = fmaxf(mx, shflx(mx, m)); }
    float x0 = 2.f * (acc - mn) / (mx - mn + 1e-8f) - 1.f;
    float dn = dis[n];
    if (half == 0) hs[n * 32 + c] = dn * x0;
    mn = x0; mx = x0;
#pragma unroll
    for (int m = 1; m <= 16; m <<= 1) { mn = fminf(mn, shflx(mn, m)); mx = fmaxf(mx, shflx(mx, m)); }
    float n0 = 2.f * (x0 - mn) / (mx - mn + 1e-8f) - 1.f;
    float outv = 0.f;
#pragma unroll
    for (int o = 0; o < 10; ++o) {
        float t = x0 * W2[c * 10 + o] + n0 * M0[o * 32 + c];
#pragma unroll
        for (int m = 1; m <= 16; m <<= 1) t += shflx(t, m);
        if (lane == o) outv = t;
    }
    if (lane < 10) out[n * 10 + lane] = b2[lane] + outv;
}

// ---------- GCN layer j: bucketed gather + GEMM + mynorm + out accum ----------
__global__ __launch_bounds__(256) void k_layer(
    const float4* __restrict__ hs_in, float4* __restrict__ hs_out,
    const float* __restrict__ dis, const int* __restrict__ rp4,
    const int* __restrict__ csr_src,
    const float* __restrict__ W, const float* __restrict__ b,
    const float* __restrict__ Mn, const float* __restrict__ Rw,
    float* __restrict__ out, int N, int israw)
{
    __shared__ float Ws[1024];     // W [k][c]
    __shared__ float bs[32];
    __shared__ float Ms[320];      // Mn_j [o][c]
    __shared__ float Rs[320];      // Rw_j [o][c]
    __shared__ float acc[NPB * 32];

    int base = blockIdx.x * NPB;
    if (base >= N) return;                       // uniform per block
    int cnodes = min(N - base, NPB);

    for (int i = threadIdx.x; i < 1024; i += 256) Ws[i] = W[i];
    for (int i = threadIdx.x; i < 320; i += 256) { Ms[i] = Mn[i]; Rs[i] = Rw[i]; }
    if (threadIdx.x < 32) bs[threadIdx.x] = b[threadIdx.x];

    // init acc with self-loop term: coalesced slab copy
    {
        const float4* slab = hs_in + (size_t)base * 8;
        float4* acc4 = (float4*)acc;
        int nf4 = cnodes * 8;
        for (int i = threadIdx.x; i < nf4; i += 256) acc4[i] = slab[i];
    }
    __syncthreads();

    int lane = threadIdx.x & 63;
    int q = lane & 7;              // channel quad: c = 4q..4q+3
    int slot = lane >> 3;          // edge slot 0..7
    int wave = threadIdx.x >> 6;

    for (int p = 0; p < NB; ++p) {
        for (int ni = wave; ni < cnodes; ni += 4) {
            int n = base + ni;
            int rs = rp4[n * NB + p], re = rp4[n * NB + p + 1];
            float4 a0 = make_float4(0.f, 0.f, 0.f, 0.f);
            float4 a1 = make_float4(0.f, 0.f, 0.f, 0.f);
            int e = rs + slot;
            for (; e + 8 < re; e += 16) {
                int s0 = csr_src[e], s1 = csr_src[e + 8];
                float4 v0 = hs_in[(size_t)s0 * 8 + q];
                float4 v1 = hs_in[(size_t)s1 * 8 + q];
                a0.x += v0.x; a0.y += v0.y; a0.z += v0.z; a0.w += v0.w;
                a1.x += v1.x; a1.y += v1.y; a1.z += v1.z; a1.w += v1.w;
            }
            if (e < re) {
                int s = csr_src[e];
                float4 v = hs_in[(size_t)s * 8 + q];
                a0.x += v.x; a0.y += v.y; a0.z += v.z; a0.w += v.w;
            }
            a0.x += a1.x; a0.y += a1.y; a0.z += a1.z; a0.w += a1.w;
#pragma unroll
            for (int m = 8; m <= 32; m <<= 1) {
                a0.x += shflx(a0.x, m); a0.y += shflx(a0.y, m);
                a0.z += shflx(a0.z, m); a0.w += shflx(a0.w, m);
            }
            if (slot == 0) {
                float4* A = (float4*)&acc[ni * 32];
                float4 c4 = A[q];
                c4.x += a0.x; c4.y += a0.y; c4.z += a0.z; c4.w += a0.w;
                A[q] = c4;
            }
        }
        __syncthreads();           // bucket phase alignment
    }

    // epilogue per node
    for (int ni = wave; ni < cnodes; ni += 4) {
        int n = base + ni;
        float dn = dis[n];
        float4 s4 = ((const float4*)&acc[ni * 32])[q];
        float4 g = make_float4(dn * s4.x, dn * s4.y, dn * s4.z, dn * s4.w);

        float gx = __shfl(g.x, slot, 64);    // lane 'slot' holds q==slot
        float gy = __shfl(g.y, slot, 64);
        float gz = __shfl(g.z, slot, 64);
        float gw = __shfl(g.w, slot, 64);
        const float4* W4 = (const float4*)Ws;
        int k0 = slot * 4;
        float4 xn;
        {
            float4 w0 = W4[(k0 + 0) * 8 + q];
            float4 w1 = W4[(k0 + 1) * 8 + q];
            float4 w2 = W4[(k0 + 2) * 8 + q];
            float4 w3 = W4[(k0 + 3) * 8 + q];
            xn.x = gx * w0.x + gy * w1.x + gz * w2.x + gw * w3.x;
            xn.y = gx * w0.y + gy * w1.y + gz * w2.y + gw * w3.y;
            xn.z = gx * w0.z + gy * w1.z + gz * w2.z + gw * w3.z;
            xn.w = gx * w0.w + gy * w1.w + gz * w2.w + gw * w3.w;
        }
#pragma unroll
        for (int m = 8; m <= 32; m <<= 1) {
            xn.x += shflx(xn.x, m); xn.y += shflx(xn.y, m);
            xn.z += shflx(xn.z, m); xn.w += shflx(xn.w, m);
        }
        const float4* B4 = (const float4*)bs;
        float4 bb = B4[q];
        xn.x += bb.x; xn.y += bb.y; xn.z += bb.z; xn.w += bb.w;

        if (slot == 0)
            hs_out[(size_t)n * 8 + q] =
                make_float4(dn * xn.x, dn * xn.y, dn * xn.z, dn * xn.w);

        float mn = fminf(fminf(xn.x, xn.y), fminf(xn.z, xn.w));
        float mx = fmaxf(fmaxf(xn.x, xn.y), fmaxf(xn.z, xn.w));
#pragma unroll
        for (int m = 1; m <= 4; m <<= 1) { mn = fminf(mn, shflx(mn, m)); mx = fmaxf(mx, shflx(mx, m)); }
        float sc = 2.f / (mx - mn + 1e-8f);
        float4 nr = make_float4((xn.x - mn) * sc - 1.f, (xn.y - mn) * sc - 1.f,
                                (xn.z - mn) * sc - 1.f, (xn.w - mn) * sc - 1.f);

        const float4* M4 = (const float4*)Ms;
        const float4* R4 = (const float4*)Rs;
        float outv = 0.f;
#pragma unroll
        for (int o = 0; o < 10; ++o) {
            float4 m4 = M4[o * 8 + q];
            float t = nr.x * m4.x + nr.y * m4.y + nr.z * m4.z + nr.w * m4.w;
            if (israw) {
                float4 r4 = R4[o * 8 + q];
                t += xn.x * r4.x + xn.y * r4.y + xn.z * r4.z + xn.w * r4.w;
            }
            t += shflx(t, 1); t += shflx(t, 2); t += shflx(t, 4);
            if (lane == o) outv = t;
        }
        if (lane < 10) out[n * 10 + lane] += outv;
    }
}

extern "C" void kernel_launch(void* const* d_in, const int* in_sizes, int n_in,
                              void* d_out, int out_size, void* d_ws, size_t ws_size,
                              hipStream_t stream)
{
    const float* x  = (const float*)d_in[0];
    const int*   ei = (const int*)d_in[1];
    const float* W1 = (const float*)d_in[2];
    const float* b1 = (const float*)d_in[3];
    const float* Wc = (const float*)d_in[4];
    const float* bc = (const float*)d_in[5];
    const float* W2 = (const float*)d_in[6];
    const float* b2 = (const float*)d_in[7];
    float* out = (float*)d_out;

    const int N = in_sizes[0] / 64;
    const int E = in_sizes[1] / 2;
    const int M = N * NB;                     // (node,bucket) rows
    const int* src = ei;
    const int* dst = ei + E;

    char* ws = (char*)d_ws;
    size_t off = 0;
    auto alloc = [&](size_t bytes) -> void* {
        void* p = ws + off;
        off = (off + bytes + 255) & ~size_t(255);
        return p;
    };
    int*   cnt     = (int*)alloc((size_t)M * 4);
    int*   rp4     = (int*)alloc((size_t)(M + 1) * 4);
    int*   cursor  = (int*)alloc((size_t)M * 4);
    int*   bsums   = (int*)alloc(1024 * 4);
    float* dis     = (float*)alloc((size_t)N * 4);
    int*   csr_src = (int*)alloc((size_t)E * 4);
    float* hs_a    = (float*)alloc((size_t)N * 32 * 4);
    float* hs_b    = (float*)alloc((size_t)N * 32 * 4);
    float* Mn      = (float*)alloc(32 * 32 * 10 * 4);
    float* Rw      = (float*)alloc(32 * 32 * 10 * 4);

    hipMemsetAsync(cnt, 0, (size_t)M * 4, stream);
    const int eb = (E + 255) / 256;
    const int sb = (M + 511) / 512;           // 782 <= 1024 for scan2
    k_hist<<<eb, 256, 0, stream>>>(src, dst, E, cnt);
    k_scan1<<<sb, 512, 0, stream>>>(cnt, M, rp4, bsums);
    k_scan2<<<1, 1024, 0, stream>>>(bsums, sb);
    k_scan3<<<sb, 512, 0, stream>>>(rp4, bsums, cnt, M, E, cursor, dis);
    k_fill<<<eb, 256, 0, stream>>>(src, dst, E, cursor, csr_src);
    k_mnorm<<<(32 * 32 * 10 + 255) / 256, 256, 0, stream>>>(W2, Mn, Rw);

    const int gb0 = (N + 3) / 4;
    k_x0<<<gb0, 256, 0, stream>>>(x, W1, b1, W2, b2, Mn, dis, hs_a, out, N);

    const int gb = (N + NPB - 1) / NPB;       // 1021 blocks, 98 nodes each
    float* hin = hs_a; float* hout = hs_b;
    for (int j = 1; j <= 31; ++j) {
        int israw = (j == 1 || j == 16) ? 1 : 0;
        k_layer<<<gb, 256, 0, stream>>>((const float4*)hin, (float4*)hout, dis, rp4,
                                        csr_src,
                                        Wc + (size_t)(j - 1) * 1024,
                                        bc + (size_t)(j - 1) * 32,
                                        Mn + (size_t)j * 320,
                                        Rw + (size_t)j * 320,
                                        out, N, israw);
        float* t = hin; hin = hout; hout = t;
    }
}